// Round 1
// baseline (189.368 us; speedup 1.0000x reference)
//
#include <hip/hip_runtime.h>

typedef unsigned short u16;
typedef __attribute__((ext_vector_type(8))) short short8;
typedef __attribute__((ext_vector_type(4))) float f32x4;

#define B_  64
#define IC  64
#define OC  64
#define NG  2048
#define MD  512

__device__ inline u16 f2b(float f) {
  // round-to-nearest-even fp32 -> bf16
  unsigned u = __float_as_uint(f);
  unsigned r = (u + 0x7FFFu + ((u >> 16) & 1u)) >> 16;
  return (u16)r;
}

// ---------------- fp32 -> bf16 cast (vectorized) ----------------
__global__ __launch_bounds__(256) void cast_bf16(const float* __restrict__ in,
                                                 u16* __restrict__ out) {
  int i = (blockIdx.x * 256 + threadIdx.x) * 4;
  float4 v = *(const float4*)(in + i);
  ushort4 o;
  o.x = f2b(v.x); o.y = f2b(v.y); o.z = f2b(v.z); o.w = f2b(v.w);
  *(ushort4*)(out + i) = o;
}

// ---------------- DCT-I matrix builders (bf16) ----------------
// M1[k][n] = cos(pi*k*n/(NG-1)) * c_n,  c_0 = c_{NG-1} = 1 else 2.   [MD][NG]
__global__ __launch_bounds__(256) void build_M1(u16* __restrict__ M1) {
  int idx = blockIdx.x * 256 + threadIdx.x;   // MD*NG elems
  int k = idx >> 11, n = idx & 2047;
  int r = (k * n) % (2 * (NG - 1));           // exact periodic reduction
  float ang = (float)r * (3.14159265358979323846f / (NG - 1));
  float v = __cosf(ang) * ((n == 0 || n == NG - 1) ? 1.0f : 2.0f);
  M1[idx] = f2b(v);
}

// M3[n][k] = cos(pi*n*k/(NG-1)) * c_k,  c_0 = 1 else 2 (k < 512).   [NG][MD]
__global__ __launch_bounds__(256) void build_M3(u16* __restrict__ M3) {
  int idx = blockIdx.x * 256 + threadIdx.x;   // NG*MD elems
  int n = idx >> 9, k = idx & 511;
  int r = (n * k) % (2 * (NG - 1));
  float ang = (float)r * (3.14159265358979323846f / (NG - 1));
  float v = __cosf(ang) * ((k == 0) ? 1.0f : 2.0f);
  M3[idx] = f2b(v);
}

// ---------------- bf16 MFMA GEMM, Bt form: C[m][n] = sum_k A[m][k]*Bt[n][k] ----
// 256 threads = 4 waves in a 2x2 grid; each wave computes (MI*16)x(NI*16).
// Tile: TM = MI*32, TN = NI*32, BK = 64. All dims assumed divisible.
template<int MI, int NI>
__global__ __launch_bounds__(256, 2) void gemm_bt(
    const u16* __restrict__ A,   // [M][K] bf16
    const u16* __restrict__ Bt,  // [N][K] bf16
    float* __restrict__ C,       // [M][N] fp32
    int K, int N) {
  constexpr int TM = MI * 32;
  constexpr int TN = NI * 32;
  constexpr int BK = 64;
  __shared__ u16 As[TM][BK];
  __shared__ u16 Bs[TN][BK];

  const int tid  = threadIdx.x;
  const int lane = tid & 63;
  const int wave = tid >> 6;
  const int wm = (wave >> 1) * (MI * 16);
  const int wn = (wave & 1) * (NI * 16);
  const long bm = (long)blockIdx.y * TM;
  const long bn = (long)blockIdx.x * TN;

  // MFMA fragment addressing (verified layout):
  // A/B operand: [row = lane&15][k = (lane>>4)*8 + j]  (8 contiguous bf16)
  const int lrow = lane & 15;
  const int lko  = (lane >> 4) * 8;

  // staging: 256 threads load rows of 64 bf16 (= 128 B) as uint4 (16 B/lane)
  const int srow = tid >> 3;           // 0..31
  const int scol = (tid & 7) * 8;      // 0,8,...,56

  f32x4 acc[MI][NI] = {};

  const u16* Ap = A  + (bm + srow) * (long)K + scol;
  const u16* Bp = Bt + (bn + srow) * (long)K + scol;

  for (int k0 = 0; k0 < K; k0 += BK) {
#pragma unroll
    for (int r = 0; r < TM / 32; ++r)
      *(uint4*)&As[srow + r * 32][scol] = *(const uint4*)(Ap + (long)r * 32 * K + k0);
#pragma unroll
    for (int r = 0; r < TN / 32; ++r)
      *(uint4*)&Bs[srow + r * 32][scol] = *(const uint4*)(Bp + (long)r * 32 * K + k0);
    __syncthreads();

#pragma unroll
    for (int kk = 0; kk < BK; kk += 32) {
      short8 af[MI], bfr[NI];
#pragma unroll
      for (int i = 0; i < MI; ++i)
        af[i] = *(const short8*)&As[wm + i * 16 + lrow][kk + lko];
#pragma unroll
      for (int j = 0; j < NI; ++j)
        bfr[j] = *(const short8*)&Bs[wn + j * 16 + lrow][kk + lko];
#pragma unroll
      for (int i = 0; i < MI; ++i)
#pragma unroll
        for (int j = 0; j < NI; ++j)
          acc[i][j] = __builtin_amdgcn_mfma_f32_16x16x32_bf16(af[i], bfr[j], acc[i][j], 0, 0, 0);
    }
    __syncthreads();
  }

  // C/D layout: col = lane&15, row = (lane>>4)*4 + reg
  const int crow = (lane >> 4) * 4;
  const int ccol = lane & 15;
#pragma unroll
  for (int i = 0; i < MI; ++i)
#pragma unroll
    for (int j = 0; j < NI; ++j) {
      long gm = bm + wm + i * 16 + crow;
      long gn = bn + wn + j * 16 + ccol;
      float* cp = C + gm * (long)N + gn;
#pragma unroll
      for (int r = 0; r < 4; ++r)
        cp[(long)r * N] = acc[i][j][r];
    }
}

// ---------------- per-mode 64x64x64 mix: omT[k][b*64+o] = sum_i xcT[k][b*64+i]*w[i][o][k]
__global__ __launch_bounds__(256, 4) void mode_mix(
    const float* __restrict__ xcT,   // [MD][B_*IC] fp32
    const float* __restrict__ w,     // [IC][OC][MD] fp32
    u16* __restrict__ omT) {         // [MD][B_*OC] bf16
  __shared__ float Lxc[4096];        // [b*64+i]
  __shared__ float Lw[4096];         // [i*64+o]
  const int k = blockIdx.x;
  const int t = threadIdx.x;
#pragma unroll
  for (int j = 0; j < 16; ++j) {
    int idx = t + j * 256;
    Lxc[idx] = xcT[(size_t)k * 4096 + idx];
    Lw[idx]  = w[(size_t)idx * MD + k];
  }
  __syncthreads();

  const int b0 = (t >> 4) << 2;      // 4 b rows per thread
  const int o0 = (t & 15) << 2;      // 4 o cols per thread
  float acc[4][4] = {};
  for (int i = 0; i < 64; ++i) {
    float xv0 = Lxc[(b0 + 0) * 64 + i];
    float xv1 = Lxc[(b0 + 1) * 64 + i];
    float xv2 = Lxc[(b0 + 2) * 64 + i];
    float xv3 = Lxc[(b0 + 3) * 64 + i];
    float4 wv = *(const float4*)&Lw[i * 64 + o0];
    acc[0][0] += xv0 * wv.x; acc[0][1] += xv0 * wv.y; acc[0][2] += xv0 * wv.z; acc[0][3] += xv0 * wv.w;
    acc[1][0] += xv1 * wv.x; acc[1][1] += xv1 * wv.y; acc[1][2] += xv1 * wv.z; acc[1][3] += xv1 * wv.w;
    acc[2][0] += xv2 * wv.x; acc[2][1] += xv2 * wv.y; acc[2][2] += xv2 * wv.z; acc[2][3] += xv2 * wv.w;
    acc[3][0] += xv3 * wv.x; acc[3][1] += xv3 * wv.y; acc[3][2] += xv3 * wv.z; acc[3][3] += xv3 * wv.w;
  }
#pragma unroll
  for (int r = 0; r < 4; ++r) {
    ushort4 p;
    p.x = f2b(acc[r][0]); p.y = f2b(acc[r][1]); p.z = f2b(acc[r][2]); p.w = f2b(acc[r][3]);
    *(ushort4*)&omT[(size_t)k * 4096 + (b0 + r) * 64 + o0] = p;
  }
}

// ---------------- bf16 transpose: omT [MD][4096] -> om [4096][MD] ----------------
__global__ __launch_bounds__(256) void transpose_om(const u16* __restrict__ omT,
                                                    u16* __restrict__ om) {
  __shared__ u16 S[64][65];
  const int bb = blockIdx.x;   // bo tile (64 tiles)
  const int kb = blockIdx.y;   // k  tile (8 tiles)
  const int t = threadIdx.x;
  const int r0 = t >> 6;       // 0..3
  const int c  = t & 63;
#pragma unroll
  for (int j = 0; j < 16; ++j) {
    int kr = r0 + j * 4;
    S[kr][c] = omT[(size_t)(kb * 64 + kr) * 4096 + bb * 64 + c];
  }
  __syncthreads();
#pragma unroll
  for (int j = 0; j < 16; ++j) {
    int br = r0 + j * 4;
    om[(size_t)(bb * 64 + br) * MD + kb * 64 + c] = S[c][br];
  }
}

extern "C" void kernel_launch(void* const* d_in, const int* in_sizes, int n_in,
                              void* d_out, int out_size, void* d_ws, size_t ws_size,
                              hipStream_t stream) {
  const float* x = (const float*)d_in[0];   // [B_][IC][NG]
  const float* w = (const float*)d_in[1];   // [IC][OC][MD]
  float* out = (float*)d_out;               // [B_][OC][NG]

  char* ws = (char*)d_ws;
  u16*  xb  = (u16*)ws;   ws += (size_t)B_ * IC * NG * 2;   // 16 MB  x in bf16
  u16*  M1  = (u16*)ws;   ws += (size_t)MD * NG * 2;        //  2 MB
  u16*  M3  = (u16*)ws;   ws += (size_t)NG * MD * 2;        //  2 MB
  float* xcT = (float*)ws; ws += (size_t)MD * B_ * IC * 4;  //  8 MB  xc^T fp32
  u16*  omT = (u16*)ws;   ws += (size_t)MD * B_ * OC * 2;   //  4 MB
  u16*  om  = (u16*)ws;   ws += (size_t)B_ * OC * MD * 2;   //  4 MB
  // total 36 MB of d_ws

  cast_bf16<<<(B_ * IC * NG / 4) / 256, 256, 0, stream>>>(x, xb);
  build_M1<<<(MD * NG) / 256, 256, 0, stream>>>(M1);
  build_M3<<<(NG * MD) / 256, 256, 0, stream>>>(M3);

  // G1: xcT[512][4096] = M1[512][2048] * xb[4096][2048]^T   (K=2048)
  gemm_bt<2, 2><<<dim3((B_ * IC) / 64, MD / 64), 256, 0, stream>>>(M1, xb, xcT, NG, B_ * IC);

  // mode mix: omT[512][4096]
  mode_mix<<<MD, 256, 0, stream>>>(xcT, w, omT);

  // transpose to om[4096][512]
  transpose_om<<<dim3((B_ * OC) / 64, MD / 64), 256, 0, stream>>>(omT, om);

  // G3: out[4096][2048] = om[4096][512] * M3[2048][512]^T   (K=512)
  gemm_bt<4, 4><<<dim3(NG / 128, (B_ * OC) / 128), 256, 0, stream>>>(om, M3, out, MD, NG);
}